// Round 9
// baseline (1638.454 us; speedup 1.0000x reference)
//
#include <hip/hip_runtime.h>
#include <math.h>

#define WW 32
#define FF 16
#define HH 64
#define LSTM_LDS 155648   // Bh 32768 + Bl 32768 + Bx 16384 + 8 waves * 9216 scratch

typedef __attribute__((ext_vector_type(8))) short bf16x8;
typedef __attribute__((ext_vector_type(4))) float f32x4;

__device__ __forceinline__ unsigned short bf16h(float f) {   // RNE round
    unsigned int u = __float_as_uint(f);
    unsigned int r = (u + 0x7FFFu + ((u >> 16) & 1u)) >> 16;
    return (unsigned short)r;
}
__device__ __forceinline__ float fsig(float v)  { return __fdividef(1.0f, 1.0f + __expf(-v)); }
__device__ __forceinline__ float ftanh(float v) { return 1.0f - __fdividef(2.0f, 1.0f + __expf(2.0f * v)); }

// trunc-split: hi = trunc-bf16(v), lo = trunc-bf16(v - hi)
__device__ __forceinline__ void tsplit8(const float* v, bf16x8& hi, bf16x8& lo) {
    #pragma unroll
    for (int i = 0; i < 8; i++) {
        unsigned int u = __float_as_uint(v[i]);
        hi[i] = (short)(u >> 16);
        float lf = v[i] - __uint_as_float(u & 0xFFFF0000u);
        lo[i] = (short)(__float_as_uint(lf) >> 16);
    }
}

// ---------------- LSTM: barrier-free per-wave recurrence ----------------
// Block = 512 threads = 8 waves; each wave owns 32 nodes AND all 256 gate
// columns -> h state never crosses waves -> ZERO barriers in the t-loop
// (within-wave DS ordering suffices). B (Wcat split fragments) is shared,
// pre-built in LDS by the whole block once. Per-wave h scratch: [plane][node]
// [dim] bf16, node-row stride 144B (non-pow2 -> banks rotate, conflict-spread).
// Numerics identical to R8: 3-term trunc-split h-path + packed-x K=32 MFMA.
__global__ __launch_bounds__(512, 2) void lstm_mfma_kernel(
    const float* __restrict__ x,      // [N,32,16]
    const float* __restrict__ W_ih,   // [256,16]
    const float* __restrict__ W_hh,   // [256,64]
    const float* __restrict__ b_ih,   // [256]
    const float* __restrict__ b_hh,   // [256]
    float* __restrict__ h_out,        // [N,64]
    int nN)
{
    extern __shared__ char sm[];
    const int OFF_BH = 0;
    const int OFF_BL = 32768;
    const int OFF_BX = 65536;
    const int OFF_SC = 81920;

    const int tid  = threadIdx.x;
    const int lane = tid & 63;
    const int wv   = tid >> 6;
    const int l15  = lane & 15;
    const int g    = lane >> 4;
    const int nb   = blockIdx.x * 256 + wv * 32;   // this wave's node base

    // ---- cooperative B build (hi/lo planes of W_hh, RNE bf16 of W_ih) ----
    for (int s = tid; s < 2048; s += 512) {        // Bh / Bl slots
        const int ct = s >> 7, q = (s >> 6) & 1, l = s & 63;
        const int col = 64 * (ct >> 2) + 16 * (ct & 3) + (l & 15);
        const int k0  = 32 * q + 8 * (l >> 4);
        const float* wr = W_hh + col * HH + k0;
        float4 a = reinterpret_cast<const float4*>(wr)[0];
        float4 b = reinterpret_cast<const float4*>(wr)[1];
        float v[8] = {a.x,a.y,a.z,a.w,b.x,b.y,b.z,b.w};
        bf16x8 hi, lo;
        tsplit8(v, hi, lo);
        *reinterpret_cast<bf16x8*>(sm + OFF_BH + (ct * 128 + q * 64 + l) * 16) = hi;
        *reinterpret_cast<bf16x8*>(sm + OFF_BL + (ct * 128 + q * 64 + l) * 16) = lo;
    }
    for (int s = tid; s < 1024; s += 512) {        // Bx slots (RNE bf16, both k-halves)
        const int ct = s >> 6, l = s & 63;
        const int col = 64 * (ct >> 2) + 16 * (ct & 3) + (l & 15);
        const float* wr = W_ih + col * FF + 8 * ((l >> 4) & 1);
        float4 a = reinterpret_cast<const float4*>(wr)[0];
        float4 b = reinterpret_cast<const float4*>(wr)[1];
        float v[8] = {a.x,a.y,a.z,a.w,b.x,b.y,b.z,b.w};
        bf16x8 bx;
        #pragma unroll
        for (int i = 0; i < 8; i++) bx[i] = (short)bf16h(v[i]);
        *reinterpret_cast<bf16x8*>(sm + OFF_BX + (ct * 64 + l) * 16) = bx;
    }

    // ---- per-lane bias (16 regs) ----
    float bias[4][4];
    #pragma unroll
    for (int dt = 0; dt < 4; dt++)
        #pragma unroll
        for (int gate = 0; gate < 4; gate++) {
            const int j = 64 * gate + 16 * dt + l15;
            bias[dt][gate] = b_ih[j] + b_hh[j];
        }

    // ---- zero own h scratch (both planes) ----
    char* scr = sm + OFF_SC + wv * 9216;
    for (int i = lane; i < 576; i += 64)
        *reinterpret_cast<int4*>(scr + i * 16) = make_int4(0, 0, 0, 0);

    __syncthreads();   // B visible; the ONLY block-wide barrier

    float cst[2][4][4];
    #pragma unroll
    for (int m = 0; m < 2; m++)
        #pragma unroll
        for (int dt = 0; dt < 4; dt++)
            #pragma unroll
            for (int r = 0; r < 4; r++) cst[m][dt][r] = 0.0f;

    for (int t = 0; t < WW; t++) {
        // ---- A fragments: h from own scratch, x packed [xh|xl] from global ----
        bf16x8 Ah0[2], Ah1[2], Al0[2], Al1[2], Ax[2];
        #pragma unroll
        for (int m = 0; m < 2; m++) {
            const char* ab = scr + (16 * m + l15) * 144 + g * 16;
            Ah0[m] = *reinterpret_cast<const bf16x8*>(ab);
            Ah1[m] = *reinterpret_cast<const bf16x8*>(ab + 64);
            Al0[m] = *reinterpret_cast<const bf16x8*>(ab + 4608);
            Al1[m] = *reinterpret_cast<const bf16x8*>(ab + 4608 + 64);
            int gn = nb + 16 * m + l15; if (gn >= nN) gn = nN - 1;
            const float* xp = x + (size_t)gn * (WW * FF) + t * FF + (g & 1) * 8;
            float4 a = reinterpret_cast<const float4*>(xp)[0];
            float4 b = reinterpret_cast<const float4*>(xp)[1];
            float v[8] = {a.x,a.y,a.z,a.w,b.x,b.y,b.z,b.w};
            bf16x8 ax;
            if (g < 2) {
                #pragma unroll
                for (int i = 0; i < 8; i++) ax[i] = (short)(__float_as_uint(v[i]) >> 16);
            } else {
                #pragma unroll
                for (int i = 0; i < 8; i++) {
                    float lf = v[i] - __uint_as_float(__float_as_uint(v[i]) & 0xFFFF0000u);
                    ax[i] = (short)(__float_as_uint(lf) >> 16);
                }
            }
            Ax[m] = ax;
        }

        #pragma unroll
        for (int dt = 0; dt < 4; dt++) {
            bf16x8 bh0[4], bh1[4], bl0[4], bl1[4], bx[4];
            #pragma unroll
            for (int gate = 0; gate < 4; gate++) {
                const int ct = 4 * gate + dt;
                bh0[gate] = *reinterpret_cast<const bf16x8*>(sm + OFF_BH + (ct * 128 + lane) * 16);
                bh1[gate] = *reinterpret_cast<const bf16x8*>(sm + OFF_BH + (ct * 128 + 64 + lane) * 16);
                bl0[gate] = *reinterpret_cast<const bf16x8*>(sm + OFF_BL + (ct * 128 + lane) * 16);
                bl1[gate] = *reinterpret_cast<const bf16x8*>(sm + OFF_BL + (ct * 128 + 64 + lane) * 16);
                bx[gate]  = *reinterpret_cast<const bf16x8*>(sm + OFF_BX + (ct * 64 + lane) * 16);
            }
            #pragma unroll
            for (int m = 0; m < 2; m++) {
                f32x4 acc[4];
                #pragma unroll
                for (int gate = 0; gate < 4; gate++) {
                    f32x4 ini = {bias[dt][gate], bias[dt][gate], bias[dt][gate], bias[dt][gate]};
                    acc[gate] = ini;
                }
                #pragma unroll
                for (int gate = 0; gate < 4; gate++) {
                    acc[gate] = __builtin_amdgcn_mfma_f32_16x16x32_bf16(Ah0[m], bh0[gate], acc[gate], 0, 0, 0);
                    acc[gate] = __builtin_amdgcn_mfma_f32_16x16x32_bf16(Al0[m], bh0[gate], acc[gate], 0, 0, 0);
                    acc[gate] = __builtin_amdgcn_mfma_f32_16x16x32_bf16(Ah0[m], bl0[gate], acc[gate], 0, 0, 0);
                    acc[gate] = __builtin_amdgcn_mfma_f32_16x16x32_bf16(Ah1[m], bh1[gate], acc[gate], 0, 0, 0);
                    acc[gate] = __builtin_amdgcn_mfma_f32_16x16x32_bf16(Al1[m], bh1[gate], acc[gate], 0, 0, 0);
                    acc[gate] = __builtin_amdgcn_mfma_f32_16x16x32_bf16(Ah1[m], bl1[gate], acc[gate], 0, 0, 0);
                    acc[gate] = __builtin_amdgcn_mfma_f32_16x16x32_bf16(Ax[m],  bx[gate],  acc[gate], 0, 0, 0);
                }
                #pragma unroll
                for (int r = 0; r < 4; r++) {
                    const float ig = fsig(acc[0][r]);
                    const float fg = fsig(acc[1][r]);
                    const float gg = ftanh(acc[2][r]);
                    const float og = fsig(acc[3][r]);
                    const float c  = fg * cst[m][dt][r] + ig * gg;
                    cst[m][dt][r] = c;
                    const float h  = og * ftanh(c);
                    const int node = 16 * m + 4 * g + r;
                    if (t < WW - 1) {
                        char* wp = scr + node * 144 + (16 * dt + l15) * 2;
                        unsigned int u = __float_as_uint(h);
                        *(short*)(wp)        = (short)(u >> 16);
                        float lf = h - __uint_as_float(u & 0xFFFF0000u);
                        *(short*)(wp + 4608) = (short)(__float_as_uint(lf) >> 16);
                    } else {
                        const int gn2 = nb + node;
                        if (gn2 < nN) h_out[(size_t)gn2 * HH + 16 * dt + l15] = h;
                    }
                }
            }
        }
        // no barrier: scratch is wave-private; DS ops are in-order per wave
    }
}

// ---------------- CSR build ----------------
__global__ void zero_int_kernel(int* __restrict__ p, int n) {
    int i = blockIdx.x * 256 + threadIdx.x;
    if (i < n) p[i] = 0;
}

__global__ void deg_int_kernel(const int* __restrict__ dst, int* __restrict__ deg, int nE, int nN) {
    int e = blockIdx.x * 256 + threadIdx.x;
    if (e < nE) {
        int d = dst[e];
        if ((unsigned)d < (unsigned)nN) atomicAdd(&deg[d], 1);
    }
}

__global__ void dis_from_deg_kernel(const int* __restrict__ deg, float* __restrict__ dis, int nN) {
    int i = blockIdx.x * 256 + threadIdx.x;
    if (i < nN) dis[i] = rsqrtf((float)deg[i] + 1.0f);
}

__global__ __launch_bounds__(1024) void scan_kernel(const int* __restrict__ deg,
                                                    int* __restrict__ row_ptr,
                                                    int* __restrict__ cursor, int nN)
{
    __shared__ int part[1024];
    const int tid = threadIdx.x;
    const int chunk = (nN + 1023) / 1024;
    const int s = tid * chunk;
    const int e = min(s + chunk, nN);
    int sum = 0;
    for (int i = s; i < e; i++) sum += deg[i];
    part[tid] = sum;
    __syncthreads();
    if (tid == 0) {
        int acc = 0;
        for (int i = 0; i < 1024; i++) { int v = part[i]; part[i] = acc; acc += v; }
    }
    __syncthreads();
    int acc = part[tid];
    for (int i = s; i < e; i++) {
        row_ptr[i] = acc;
        cursor[i]  = acc;
        acc += deg[i];
    }
}

__global__ void place_kernel(const int* __restrict__ src, const int* __restrict__ dst,
                             const float* __restrict__ dis, int* __restrict__ cursor,
                             int* __restrict__ csr_src, float* __restrict__ csr_dis,
                             int nE, int nN)
{
    int e = blockIdx.x * 256 + threadIdx.x;
    if (e >= nE) return;
    int s = src[e], d = dst[e];
    if ((unsigned)s >= (unsigned)nN || (unsigned)d >= (unsigned)nN) return;
    int pos = atomicAdd(&cursor[d], 1);
    csr_src[pos] = s;
    csr_dis[pos] = dis[s];
}

// ---------------- xw = act(in) @ W ----------------
template<bool RELU_BIAS, bool WRITE_AGG>
__global__ void xw_kernel(const float* __restrict__ A, const float* __restrict__ W,
                          const float* __restrict__ bias, const float* __restrict__ dis,
                          float* __restrict__ xw_out, float* __restrict__ agg_out, int nN)
{
    const int wave = threadIdx.x >> 6;
    const int lane = threadIdx.x & 63;
    const int n = blockIdx.x * 4 + wave;
    if (n >= nN) return;
    const float* arow = A + (size_t)n * HH;
    float acc = 0.0f;
    #pragma unroll
    for (int k = 0; k < HH; k++) {
        float a = arow[k];
        if (RELU_BIAS) a = fmaxf(a + bias[k], 0.0f);
        acc = fmaf(a, W[k * HH + lane], acc);
    }
    xw_out[(size_t)n * HH + lane] = acc;
    if (WRITE_AGG) {
        const float d = dis[n];
        agg_out[(size_t)n * HH + lane] = acc * d * d;
    }
}

// ---------------- gather: wave per node, no atomics ----------------
template<bool FINAL>
__global__ void gather_kernel(const float* __restrict__ xw, const float* __restrict__ dis,
                              const int* __restrict__ row_ptr, const int* __restrict__ deg,
                              const int* __restrict__ csr_src, const float* __restrict__ csr_dis,
                              float* __restrict__ agg_out,
                              const float* __restrict__ b2, const float* __restrict__ W_lin,
                              const float* __restrict__ b_lin, float* __restrict__ out, int nN)
{
    const int wave = threadIdx.x >> 6;
    const int lane = threadIdx.x & 63;
    const int n = blockIdx.x * 4 + wave;
    if (n >= nN) return;
    const float dn = dis[n];
    float v = xw[(size_t)n * HH + lane] * dn;   // self-loop
    const int start = row_ptr[n];
    const int cnt   = deg[n];
    int i = start;
    const int end = start + cnt;
    for (; i + 1 < end; i += 2) {
        int s0 = csr_src[i];     float c0 = csr_dis[i];
        int s1 = csr_src[i + 1]; float c1 = csr_dis[i + 1];
        v = fmaf(xw[(size_t)s0 * HH + lane], c0, v);
        v = fmaf(xw[(size_t)s1 * HH + lane], c1, v);
    }
    if (i < end) {
        int s0 = csr_src[i]; float c0 = csr_dis[i];
        v = fmaf(xw[(size_t)s0 * HH + lane], c0, v);
    }
    v *= dn;
    if (FINAL) {
        float val = fmaxf(v + b2[lane], 0.0f) * W_lin[lane];
        #pragma unroll
        for (int off = 32; off > 0; off >>= 1) val += __shfl_down(val, off);
        if (lane == 0) out[n] = val + b_lin[0];
    } else {
        agg_out[(size_t)n * HH + lane] = v;
    }
}

// ---------------- fallback: atomic scatter path ----------------
__global__ void scatter_kernel(const float* __restrict__ xw, const float* __restrict__ dis,
                               const int* __restrict__ src, const int* __restrict__ dst,
                               float* __restrict__ agg, int nE, int nN)
{
    const int e = blockIdx.x * 4 + (threadIdx.x >> 6);
    const int lane = threadIdx.x & 63;
    if (e >= nE) return;
    int s = src[e], d = dst[e];
    if ((unsigned)s >= (unsigned)nN || (unsigned)d >= (unsigned)nN) return;
    const float coef = dis[s] * dis[d];
    const float v = xw[(size_t)s * HH + lane] * coef;
    atomicAdd(&agg[(size_t)d * HH + lane], v);
}

__global__ void head_kernel(const float* __restrict__ agg, const float* __restrict__ b2,
                            const float* __restrict__ W_lin, const float* __restrict__ b_lin,
                            float* __restrict__ out, int nN)
{
    const int wave = threadIdx.x >> 6;
    const int lane = threadIdx.x & 63;
    const int n = blockIdx.x * 4 + wave;
    if (n >= nN) return;
    float v = fmaxf(agg[(size_t)n * HH + lane] + b2[lane], 0.0f) * W_lin[lane];
    #pragma unroll
    for (int off = 32; off > 0; off >>= 1) v += __shfl_down(v, off);
    if (lane == 0) out[n] = v + b_lin[0];
}

extern "C" void kernel_launch(void* const* d_in, const int* in_sizes, int n_in,
                              void* d_out, int out_size, void* d_ws, size_t ws_size,
                              hipStream_t stream)
{
    const float* x     = (const float*)d_in[0];
    const int*   edge  = (const int*)d_in[1];
    const float* W_ih  = (const float*)d_in[2];
    const float* W_hh  = (const float*)d_in[3];
    const float* b_ih  = (const float*)d_in[4];
    const float* b_hh  = (const float*)d_in[5];
    const float* W1    = (const float*)d_in[6];
    const float* b1    = (const float*)d_in[7];
    const float* W2    = (const float*)d_in[8];
    const float* b2    = (const float*)d_in[9];
    const float* W_lin = (const float*)d_in[10];
    const float* b_lin = (const float*)d_in[11];
    float* out = (float*)d_out;

    const int nN = in_sizes[0] / (WW * FF);   // 100000
    const int nE = in_sizes[1] / 2;           // 1600000
    const int* src = edge;
    const int* dst = edge + nE;

    // allow >64KB dynamic LDS (idempotent; not a stream op -> capture-safe)
    hipFuncSetAttribute(reinterpret_cast<const void*>(lstm_mfma_kernel),
                        hipFuncAttributeMaxDynamicSharedMemorySize, LSTM_LDS);

    float* ws = (float*)d_ws;
    const size_t npad = ((size_t)nN + 255) & ~(size_t)255;
    float* dis = ws;                           // [N]
    float* A   = ws + npad;                    // [N,64]
    float* B   = A + (size_t)nN * HH;          // [N,64]
    float* C   = B + (size_t)nN * HH;          // [N,64]
    int*   deg_i   = (int*)(C + (size_t)nN * HH);   // [N]
    int*   row_ptr = deg_i + npad;                  // [N]
    int*   cursor  = row_ptr + npad;                // [N]
    int*   csr_src = cursor + npad;                 // [E]
    float* csr_dis = (float*)(csr_src + nE);        // [E]

    const size_t need = (npad + 3 * (size_t)nN * HH + 3 * npad + 2 * (size_t)nE) * 4;
    const bool use_csr = (ws_size >= need);

    const int gN256 = (nN + 255) / 256;
    const int gE256 = (nE + 255) / 256;
    const int gN4   = (nN + 3) / 4;
    const int gLSTM = (nN + 255) / 256;

    if (use_csr) {
        zero_int_kernel<<<gN256, 256, 0, stream>>>(deg_i, nN);
        deg_int_kernel<<<gE256, 256, 0, stream>>>(dst, deg_i, nE, nN);
        dis_from_deg_kernel<<<gN256, 256, 0, stream>>>(deg_i, dis, nN);
        scan_kernel<<<1, 1024, 0, stream>>>(deg_i, row_ptr, cursor, nN);
        place_kernel<<<gE256, 256, 0, stream>>>(src, dst, dis, cursor, csr_src, csr_dis, nE, nN);

        lstm_mfma_kernel<<<gLSTM, 512, LSTM_LDS, stream>>>(x, W_ih, W_hh, b_ih, b_hh, A, nN);

        xw_kernel<false, false><<<gN4, 256, 0, stream>>>(A, W1, nullptr, dis, B, nullptr, nN);
        gather_kernel<false><<<gN4, 256, 0, stream>>>(B, dis, row_ptr, deg_i, csr_src, csr_dis,
                                                      C, nullptr, nullptr, nullptr, nullptr, nN);
        xw_kernel<true, false><<<gN4, 256, 0, stream>>>(C, W2, b1, dis, B, nullptr, nN);
        gather_kernel<true><<<gN4, 256, 0, stream>>>(B, dis, row_ptr, deg_i, csr_src, csr_dis,
                                                     nullptr, b2, W_lin, b_lin, out, nN);
    } else {
        zero_int_kernel<<<gN256, 256, 0, stream>>>(deg_i, nN);
        deg_int_kernel<<<gE256, 256, 0, stream>>>(dst, deg_i, nE, nN);
        dis_from_deg_kernel<<<gN256, 256, 0, stream>>>(deg_i, dis, nN);

        lstm_mfma_kernel<<<gLSTM, 512, LSTM_LDS, stream>>>(x, W_ih, W_hh, b_ih, b_hh, A, nN);

        xw_kernel<false, true><<<gN4, 256, 0, stream>>>(A, W1, nullptr, dis, B, C, nN);
        scatter_kernel<<<(nE + 3) / 4, 256, 0, stream>>>(B, dis, src, dst, C, nE, nN);

        xw_kernel<true, true><<<gN4, 256, 0, stream>>>(C, W2, b1, dis, A, B, nN);
        scatter_kernel<<<(nE + 3) / 4, 256, 0, stream>>>(A, dis, src, dst, B, nE, nN);

        head_kernel<<<gN4, 256, 0, stream>>>(B, b2, W_lin, b_lin, out, nN);
    }
}